// Round 5
// baseline (461.900 us; speedup 1.0000x reference)
//
#include <hip/hip_runtime.h>
#include <hip/hip_cooperative_groups.h>
#include <hip/hip_bf16.h>
#include <float.h>
#include <math.h>

namespace cg = cooperative_groups;

#define NPTS 500
#define NP12 12
#define NPP  4
#define SLOPE 0.01f
#define NBLK 256

__device__ __forceinline__ float lrelu(float x) { return x > 0.f ? x : SLOPE * x; }

// ---------------------------------------------------------------------------
// All device pointers in one kernarg struct (single cooperative kernel).
// ---------------------------------------------------------------------------
struct P3DParams {
    const float *img, *cloud, *img_tar, *cloud_tar, *current_feat, *target_feat;
    const float *Wc1, *bc1, *Wc2, *bc2;       // ifeat
    const float *Wp1, *bp1, *Wp2, *bp2;       // pfeat
    const float *Wfc1, *bfc1, *Wfc2, *bfc2;
    const float *Wf2, *bf2;
    const float *Wpn1, *bpn1, *Wpn2, *bpn2, *Wpn3, *bpn3;
    int *inds, *inds_self2, *inds_pp;
    float *w_ct, *w_cc, *partials;
    float *P_ct, *P_c, *F_it, *F_ic;
    float *img_diff, *cloud_diff, *spd, *sid;
    float *fuse_i, *fuse_p, *fuse_t_c, *x1, *x2, *tf;
    float *out;
};

// ---------------------------------------------------------------------------
// Stage A1: KNN task (one block-task = 4 wave-queries). Also emits softmax
// numerators e=exp(-sqrt(d2+eps)) for p<2 (bv IS the selected distance) and
// per-wave partial sums into partials[wid] (summed redundantly in stage B).
// ---------------------------------------------------------------------------
__device__ __forceinline__ void knn_task(const P3DParams& p, int task, int tid,
                                         float* sm) {
    float* c_lds  = sm;
    float* ct_lds = sm + 1504;
    for (int i = tid; i < 1500; i += 256) {
        c_lds[i]  = p.cloud[i];
        ct_lds[i] = p.cloud_tar[i];
    }
    __syncthreads();

    const int wid  = task * 4 + (tid >> 6);   // < 1500 always (375 tasks)
    const int lane = tid & 63;
    const int prob = wid / NPTS;
    const int n    = wid % NPTS;

    const float* Q; const float* R; int k; int* out; float* w;
    if (prob == 0)      { Q = ct_lds; R = c_lds;  k = NP12; out = p.inds;       w = p.w_ct; }
    else if (prob == 1) { Q = ct_lds; R = ct_lds; k = NP12; out = p.inds_self2; w = p.w_cc; }
    else                { Q = c_lds;  R = ct_lds; k = NPP;  out = p.inds_pp;    w = nullptr; }

    const float qx = Q[n * 3 + 0];
    const float qy = Q[n * 3 + 1];
    const float qz = Q[n * 3 + 2];

    float d[8];
#pragma unroll
    for (int j = 0; j < 8; ++j) {
        int idx = j * 64 + lane;
        float dd = FLT_MAX;
        if (idx < NPTS) {
            float dx = qx - R[idx * 3 + 0];
            float dy = qy - R[idx * 3 + 1];
            float dz = qz - R[idx * 3 + 2];
            dd = dx * dx + dy * dy + dz * dz;
        }
        d[j] = dd;
    }

    float sum_e = 0.f;
    for (int t = 0; t < k; ++t) {
        float bv = d[0]; int bj = 0;
#pragma unroll
        for (int j = 1; j < 8; ++j) {
            if (d[j] < bv) { bv = d[j]; bj = j; }
        }
        int bidx = bj * 64 + lane;
#pragma unroll
        for (int s = 32; s >= 1; s >>= 1) {
            float ov = __shfl_xor(bv, s, 64);
            int   oi = __shfl_xor(bidx, s, 64);
            if (ov < bv || (ov == bv && oi < bidx)) { bv = ov; bidx = oi; }
        }
        if (w) {
            float e = expf(-sqrtf(bv + 1e-12f));   // all lanes identical
            sum_e += e;
            if (lane == 0) w[n * NP12 + t] = e;
        }
        if (lane == 0) out[n * k + t] = bidx;
        bool mine = (lane == (bidx & 63));
        int jj = bidx >> 6;
#pragma unroll
        for (int j = 0; j < 8; ++j) {
            if (mine && jj == j) d[j] = FLT_MAX;
        }
    }
    if (w && lane == 0) p.partials[wid] = sum_e;
}

// ---------------------------------------------------------------------------
// Stage A2: fused 2-layer conv chain task f in [0,32): chain=f>>3, colb=f&7.
// Register-blocked (verified in round 4's featchain_kernel).
// ---------------------------------------------------------------------------
__device__ __forceinline__ void featchain_task(const P3DParams& p, int f, int tid,
                                               float* sm) {
    float* xin = sm;          // 32*64
    float* mid = sm + 2048;   // 64*64

    const int chain = f >> 3;
    const int wave = __builtin_amdgcn_readfirstlane(tid >> 6);
    const int lane = tid & 63;
    const int col0 = (f & 7) * 64;

    const float *src, *W1, *B1, *W2, *B2;
    float* dst;
    int Cin; bool coord;
    switch (chain) {
        case 0: src = p.cloud_tar; W1 = p.Wp1; B1 = p.bp1; W2 = p.Wp2; B2 = p.bp2; dst = p.P_ct; Cin = 3;  coord = true;  break;
        case 1: src = p.cloud;     W1 = p.Wp1; B1 = p.bp1; W2 = p.Wp2; B2 = p.bp2; dst = p.P_c;  Cin = 3;  coord = true;  break;
        case 2: src = p.img_tar;   W1 = p.Wc1; B1 = p.bc1; W2 = p.Wc2; B2 = p.bc2; dst = p.F_it; Cin = 32; coord = false; break;
        default:src = p.img;       W1 = p.Wc1; B1 = p.bc1; W2 = p.Wc2; B2 = p.bc2; dst = p.F_ic; Cin = 32; coord = false; break;
    }

    for (int idx = tid; idx < Cin * 64; idx += 256) {
        int i = idx >> 6;
        int cl = idx & 63;
        int nn = col0 + cl;
        float v = 0.f;
        if (nn < NPTS) v = coord ? src[nn * 3 + i] : src[i * NPTS + nn];
        xin[i * 64 + cl] = v;
    }
    __syncthreads();

    {
        const int m0 = wave * 16;
        float accm[16];
#pragma unroll
        for (int r = 0; r < 16; ++r) accm[r] = B1[m0 + r];
        for (int i = 0; i < Cin; ++i) {
            float xv = xin[i * 64 + lane];
#pragma unroll
            for (int r = 0; r < 16; ++r)
                accm[r] = fmaf(W1[(m0 + r) * Cin + i], xv, accm[r]);
        }
#pragma unroll
        for (int r = 0; r < 16; ++r)
            mid[(m0 + r) * 64 + lane] = lrelu(accm[r]);
    }
    __syncthreads();

    const int nn = col0 + lane;
    for (int og = 0; og < 4; ++og) {
        const int o0 = wave * 32 + og * 8;
        float acc[8];
#pragma unroll
        for (int r = 0; r < 8; ++r) acc[r] = B2[o0 + r];
#pragma unroll 16
        for (int m = 0; m < 64; ++m) {
            float xv = mid[m * 64 + lane];
#pragma unroll
            for (int r = 0; r < 8; ++r)
                acc[r] = fmaf(W2[(o0 + r) * 64 + m], xv, acc[r]);
        }
        if (nn < NPTS) {
#pragma unroll
            for (int r = 0; r < 8; ++r)
                dst[(o0 + r) * NPTS + nn] = acc[r];
        }
    }
}

// ---------------------------------------------------------------------------
// Stage B: diff + sdiff fused, one channel per block (128 tasks). The gather
// source rows (F_ic, P_c, then img_diff/cloud_diff) live in LDS, so sdiff
// avoids a global round-trip. Each block redundantly reduces the 1000
// softmax partials (no atomics / extra grid sync needed).
// ---------------------------------------------------------------------------
__device__ __forceinline__ void diff_sdiff_task(const P3DParams& p, int ch, int tid,
                                                float* sm) {
    float* sFic = sm;
    float* sPc  = sm + 512;
    float* sID  = sm + 1024;
    float* sCD  = sm + 1536;
    float* red  = sm + 2048;   // 8 floats

    float l0 = 0.f, l1 = 0.f;
    for (int i = tid; i < 500; i += 256) {
        l0 += p.partials[i];
        l1 += p.partials[500 + i];
    }
#pragma unroll
    for (int s = 32; s >= 1; s >>= 1) {
        l0 += __shfl_xor(l0, s, 64);
        l1 += __shfl_xor(l1, s, 64);
    }
    if ((tid & 63) == 0) {
        red[(tid >> 6) * 2]     = l0;
        red[(tid >> 6) * 2 + 1] = l1;
    }
    for (int i = tid; i < 500; i += 256) {
        sFic[i] = p.F_ic[ch * NPTS + i];
        sPc[i]  = p.P_c[ch * NPTS + i];
    }
    __syncthreads();
    const float inv0 = 1.f / (red[0] + red[2] + red[4] + red[6]);
    const float inv1 = 1.f / (red[1] + red[3] + red[5] + red[7]);

    for (int n = tid; n < 500; n += 256) {
        float maxI = -FLT_MAX, maxP = -FLT_MAX;
#pragma unroll
        for (int j = 0; j < NP12; ++j) {
            int idx  = p.inds[n * NP12 + j];
            float wv = p.w_ct[n * NP12 + j] * inv0;
            maxI = fmaxf(maxI, sFic[idx] * wv);
            maxP = fmaxf(maxP, sPc[idx] * wv);
        }
        float idv = p.F_it[ch * NPTS + n] - maxI;
        float cdv = p.P_ct[ch * NPTS + n] - maxP;
        p.img_diff[ch * NPTS + n]   = idv;
        p.cloud_diff[ch * NPTS + n] = cdv;
        sID[n] = idv;
        sCD[n] = cdv;
    }
    __syncthreads();
    for (int n = tid; n < 500; n += 256) {
        float maxP = -FLT_MAX, maxI = -FLT_MAX;
#pragma unroll
        for (int j = 0; j < NP12; ++j) {
            int idx  = p.inds_self2[n * NP12 + j];
            float wv = p.w_cc[n * NP12 + j] * inv1;
            maxP = fmaxf(maxP, sCD[idx] * wv);
            maxI = fmaxf(maxI, sID[idx] * wv);
        }
        p.spd[ch * NPTS + n] = maxP;
        p.sid[ch * NPTS + n] = maxI;
    }
}

// ---------------------------------------------------------------------------
// GEMM core (verified round 4): Y[r,n] = bias + sum_k W[r*ldW+kOffW+k]*X[k,n],
// X = concat(X1:K1, X2:K2). wave -> 2 rows x 64 cols; K chunked by 32 in LDS;
// register double-buffer for the next chunk. No lambdas (clang crash, r3).
// Over-reads <=12 floats past a row end: arena guard gaps cover it.
// ---------------------------------------------------------------------------
__device__ __forceinline__ const float* gemm_src(
        const float* __restrict__ X1, int K1, const float* __restrict__ X2,
        int k, int coloff) {
    if (k < K1) return X1 + (size_t)k * NPTS + coloff;
    return X2 + (size_t)(k - K1) * NPTS + coloff;
}

__device__ __forceinline__ void gemm_dev(
        const float* __restrict__ W, int ldW, int kOffW,
        const float* __restrict__ Bv,
        const float* __restrict__ X1, int K1,
        const float* __restrict__ X2, int K2,
        float* __restrict__ Y, int r0, int col0,
        int mode, const float* __restrict__ aux, float* Xs) {
    const int tid  = threadIdx.x;
    const int lane = tid & 63;
    const int n    = col0 + lane;
    const int srow = tid >> 3;
    const int scol = (tid & 7) * 8;
    const int coloff = col0 + scol;

    float acc0 = Bv ? Bv[r0]     : 0.f;
    float acc1 = Bv ? Bv[r0 + 1] : 0.f;

    const int nchunks = (K1 + K2) >> 5;

    const float* s = gemm_src(X1, K1, X2, srow, coloff);
    float4 ra = *(const float4*)s;
    float4 rb = *(const float4*)(s + 4);

    for (int c = 0; c < nchunks; ++c) {
        __syncthreads();
        float* dsh = &Xs[srow * 64 + scol];
        *(float4*)dsh       = ra;
        *(float4*)(dsh + 4) = rb;
        if (c + 1 < nchunks) {
            const float* sn = gemm_src(X1, K1, X2, (c + 1) * 32 + srow, coloff);
            ra = *(const float4*)sn;
            rb = *(const float4*)(sn + 4);
        }
        __syncthreads();
        const float* w0 = &W[(size_t)r0 * ldW + kOffW + c * 32];
        const float* w1 = w0 + ldW;
#pragma unroll
        for (int k = 0; k < 32; ++k) {
            float xv = Xs[k * 64 + lane];
            acc0 = fmaf(w0[k], xv, acc0);
            acc1 = fmaf(w1[k], xv, acc1);
        }
    }

    if (n < NPTS) {
        float v0 = acc0, v1 = acc1;
        if (mode == 1) { v0 = lrelu(v0); v1 = lrelu(v1); }
        else if (mode == 2) {
            v0 *= aux[r0 * NPTS + n];
            v1 *= aux[(r0 + 1) * NPTS + n];
        }
        Y[r0 * NPTS + n]       = v0;
        Y[(r0 + 1) * NPTS + n] = v1;
    }
}

// ---------------------------------------------------------------------------
// The whole pipeline as ONE cooperative kernel. 256 blocks x 256 threads
// (1 block/CU guaranteed co-resident). 7 grid syncs replace 11 dispatch
// boundaries. Shared-memory arena sized for the largest stage (featchain,
// 24576 B).
// ---------------------------------------------------------------------------
__global__ __launch_bounds__(256) void mega_kernel(P3DParams p) {
    cg::grid_group grid = cg::this_grid();
    __shared__ __align__(16) float smem[6144];
    const int tid = threadIdx.x;
    const int bid = blockIdx.x;
    const int wave = __builtin_amdgcn_readfirstlane(tid >> 6);

    // ---- A: knn (tasks 0..374) + featchain (tasks 375..406) ----
    for (int task = bid; task < 407; task += NBLK) {
        __syncthreads();   // smem reuse across grid-stride iterations
        if (task < 375) knn_task(p, task, tid, smem);
        else            featchain_task(p, task - 375, tid, smem);
    }
    grid.sync();

    // ---- B: diff + sdiff, one channel per block ----
    if (bid < 128) diff_sdiff_task(p, bid, tid, smem);
    grid.sync();

    // ---- C: fc1 (y<8 -> fuse_i) + fc2 (y>=8 -> fuse_p), 128 tasks ----
    if (bid < 128) {
        const int y = bid >> 3, x = bid & 7;
        const int r0 = (y & 7) * 8 + wave * 2;
        if (y < 8)
            gemm_dev(p.Wfc1, 256, 0, p.bfc1, p.img_diff, 128, p.spd, 128,
                     p.fuse_i, r0, x * 64, 0, nullptr, smem);
        else
            gemm_dev(p.Wfc2, 256, 0, p.bfc2, p.cloud_diff, 128, p.sid, 128,
                     p.fuse_p, r0, x * 64, 0, nullptr, smem);
    }
    grid.sync();

    // ---- D: fuse2 (160,500), 160 tasks ----
    if (bid < 160) {
        const int y = bid >> 3, x = bid & 7;
        gemm_dev(p.Wf2, 128, 0, p.bf2, p.fuse_p, 64, p.fuse_i, 64,
                 p.fuse_t_c, y * 8 + wave * 2, x * 64, 0, nullptr, smem);
    }
    grid.sync();

    // ---- E: pn1 (256,500), 256 tasks ----
    {
        const int y = bid >> 3, x = bid & 7;
        gemm_dev(p.Wpn1, 160, 0, p.bpn1, p.fuse_t_c, 160, nullptr, 0,
                 p.x1, y * 8 + wave * 2, x * 64, 0, nullptr, smem);
    }
    grid.sync();

    // ---- F: pn2 (1024,500) + lrelu, 1024 tasks grid-stride ----
    for (int t = bid; t < 1024; t += NBLK) {
        const int y = t >> 3, x = t & 7;
        gemm_dev(p.Wpn2, 256, 0, p.bpn2, p.x1, 256, nullptr, 0,
                 p.x2, y * 8 + wave * 2, x * 64, 1, nullptr, smem);
    }
    grid.sync();

    // ---- G: pn3 (160,500), K=1024, x target_feat, 160 tasks ----
    if (bid < 160) {
        const int y = bid >> 3, x = bid & 7;
        gemm_dev(p.Wpn3, 1024, 0, p.bpn3, p.x2, 1024, nullptr, 0,
                 p.tf, y * 8 + wave * 2, x * 64, 2, p.target_feat, smem);
    }
    grid.sync();

    // ---- H: out = current_feat + mean_4 gather(tf) ----
    for (int gid = bid * 256 + tid; gid < 160 * NPTS; gid += NBLK * 256) {
        int ch = gid / NPTS;
        int n  = gid % NPTS;
        float s = 0.f;
#pragma unroll
        for (int j = 0; j < NPP; ++j)
            s += p.tf[ch * NPTS + p.inds_pp[n * NPP + j]];
        p.out[gid] = p.current_feat[gid] + 0.25f * s;
    }
}

// ---------------------------------------------------------------------------
extern "C" void kernel_launch(void* const* d_in, const int* in_sizes, int n_in,
                              void* d_out, int out_size, void* d_ws, size_t ws_size,
                              hipStream_t stream) {
    P3DParams prm;
    prm.img          = (const float*)d_in[0];
    prm.cloud        = (const float*)d_in[1];
    prm.img_tar      = (const float*)d_in[2];
    prm.cloud_tar    = (const float*)d_in[3];
    prm.current_feat = (const float*)d_in[4];
    prm.target_feat  = (const float*)d_in[5];
    prm.Wc1 = (const float*)d_in[6];  prm.bc1 = (const float*)d_in[7];
    prm.Wc2 = (const float*)d_in[8];  prm.bc2 = (const float*)d_in[9];
    prm.Wp1 = (const float*)d_in[10]; prm.bp1 = (const float*)d_in[11];
    prm.Wp2 = (const float*)d_in[12]; prm.bp2 = (const float*)d_in[13];
    prm.Wfc1 = (const float*)d_in[14]; prm.bfc1 = (const float*)d_in[15];
    prm.Wfc2 = (const float*)d_in[16]; prm.bfc2 = (const float*)d_in[17];
    prm.Wf2  = (const float*)d_in[18]; prm.bf2  = (const float*)d_in[19];
    prm.Wpn1 = (const float*)d_in[20]; prm.bpn1 = (const float*)d_in[21];
    prm.Wpn2 = (const float*)d_in[22]; prm.bpn2 = (const float*)d_in[23];
    prm.Wpn3 = (const float*)d_in[24]; prm.bpn3 = (const float*)d_in[25];

    // ws arena (floats); 64-float guard gaps cover GEMM staging over-reads.
    float* ws = (float*)d_ws;
    size_t off = 0;
    auto alloc = [&](size_t nfl) { float* q = ws + off; off += ((nfl + 63) & ~size_t(63)) + 64; return q; };
    prm.inds       = (int*)alloc(6000);
    prm.inds_self2 = (int*)alloc(6000);
    prm.inds_pp    = (int*)alloc(2000);
    prm.w_ct       = alloc(6000);
    prm.w_cc       = alloc(6000);
    prm.partials   = alloc(1000);
    prm.P_ct       = alloc(64000);
    prm.P_c        = alloc(64000);
    prm.F_it       = alloc(64000);
    prm.F_ic       = alloc(64000);
    prm.img_diff   = alloc(64000);
    prm.cloud_diff = alloc(64000);
    prm.spd        = alloc(64000);
    prm.sid        = alloc(64000);
    prm.fuse_i     = alloc(32000);
    prm.fuse_p     = alloc(32000);
    prm.fuse_t_c   = alloc(80000);
    prm.x1         = alloc(128000);
    prm.x2         = alloc(512000);
    prm.tf         = alloc(80000);
    prm.out        = (float*)d_out;

    void* args[] = { &prm };
    hipLaunchCooperativeKernel((void*)mega_kernel, dim3(NBLK), dim3(256),
                               args, 0, stream);
}